// Round 1
// 189.138 us; speedup vs baseline: 1.0306x; 1.0306x over previous
//
#include <hip/hip_runtime.h>

typedef float f32x4 __attribute__((ext_vector_type(4)));
typedef _Float16 f16x8 __attribute__((ext_vector_type(8)));
typedef int i32x4 __attribute__((ext_vector_type(4)));

__device__ __forceinline__ unsigned short f2h_bits(float f) {
    _Float16 h = (_Float16)f;
    return __builtin_bit_cast(unsigned short, h);
}
__device__ __forceinline__ float sigmoidf(float x) { return 1.0f / (1.0f + expf(-x)); }

// ---------------------------------------------------------------------------
// Setup A (33 blocks x 256) — UNCHANGED verified kernel.
// ---------------------------------------------------------------------------
__global__ void fractal_setup_a(const float* __restrict__ csl, const float* __restrict__ cls,
                                const float* __restrict__ sp, const float* __restrict__ sdl,
                                float* __restrict__ smg, float* __restrict__ csmg,
                                float* __restrict__ tbl) {
    const int tid = threadIdx.x;
    if (blockIdx.x < 32) {
        const int w = tid >> 6;
        const int lane = tid & 63;
        const int r = blockIdx.x * 4 + w;          // 0..127
        const int node = r & 63;
        const int side = r >> 6;
        const float v = csl[node * 128 + side * 64 + lane];
        float mx = v;
#pragma unroll
        for (int msk = 1; msk < 64; msk <<= 1) mx = fmaxf(mx, __shfl_xor(mx, msk, 64));
        const float e = expf(v - mx);
        float sum = e;
#pragma unroll
        for (int msk = 1; msk < 64; msk <<= 1) sum += __shfl_xor(sum, msk, 64);
        smg[r * 64 + lane] = e / sum;
    } else {
        if (tid < 64) {
            const float* rowp = cls + tid * 16;
            float mx = -1e30f;
            for (int j = 0; j < 16; ++j) mx = fmaxf(mx, rowp[j]);
            float ssum = 0.f;
            for (int j = 0; j < 16; ++j) ssum += expf(rowp[j] - mx);
            const float inv = 1.0f / ssum;
            for (int j = 0; j < 16; ++j) csmg[tid * 16 + j] = expf(rowp[j] - mx) * inv;
        } else if (tid >= 128 && tid < 192) {
            tbl[tid - 128] = expf(-sp[tid - 128]);
        } else if (tid >= 192) {
            tbl[64 + tid - 192] = sigmoidf(sdl[tid - 192]);
        }
    }
}

// ---------------------------------------------------------------------------
// Setup B (45 blocks x 256): verified R10 packing, EXTENDED with
//  - fused final-step fragments [RC; LmRC] where RC = R@Csm, LmRC = (L-R)@Csm
//    (64x16 each), packed as 4 A-fragments with row = class (no tau)
//  - row0[128]: R[0,:] and (L-R)[0,:] for the direct step-1 init.
// ---------------------------------------------------------------------------
__global__ void fractal_setup_b(const float* __restrict__ smg, const float* __restrict__ csmg,
                                unsigned short* __restrict__ frag_out,
                                float* __restrict__ row0) {
    const int e = blockIdx.x * 256 + threadIdx.x;
    if (e < 8192) {
        const int j = e & 7;
        const int l = (e >> 3) & 63;
        const int fi = e >> 9;
        const int t = fi >> 2, c = fi & 3;
        const int i = l & 15;
        const int n = 8 * (i >> 2) + (i & 3) + 4 * (t & 1) + 32 * (t >> 1);  // tau(t,i)
        const int k0 = (c & 1) * 32 + (l >> 4) * 8 + j;   // node index 0..63
        float v;
        if (c < 2) v = smg[(64 + k0) * 64 + n];                         // R
        else       v = smg[k0 * 64 + n] - smg[(64 + k0) * 64 + n];      // L - R
        frag_out[e] = f2h_bits(v);
    } else if (e < 9216) {
        const int e2 = e - 8192;   // 0..1023  (plain Csm frags, kept for md==0/legacy)
        const int j = e2 & 7;
        const int l = (e2 >> 3) & 63;
        const int c = e2 >> 9;
        const int n = l & 15;
        const int k = c * 32 + (l >> 4) * 8 + j;
        frag_out[8192 + e2] = f2h_bits(csmg[k * 16 + n]);
    } else if (e < 11264) {
        // Fused final-step fragments: A[class, k] with
        //   f=0,1 -> RC[k, class], f=2,3 -> LmRC[k, class], k = (f&1)*32 + koff
        const int e3 = e - 9216;            // 0..2047
        const int f = e3 >> 9;              // 0..3
        const int rem = e3 & 511;
        const int j = rem & 7;
        const int l = (rem >> 3) & 63;
        const int cls = l & 15;
        const int k = (f & 1) * 32 + ((l >> 4) << 3) + j;   // node 0..63
        float acc = 0.f;
        if (f < 2) {
            for (int n = 0; n < 64; ++n)
                acc += smg[(64 + k) * 64 + n] * csmg[n * 16 + cls];
        } else {
            for (int n = 0; n < 64; ++n)
                acc += (smg[k * 64 + n] - smg[(64 + k) * 64 + n]) * csmg[n * 16 + cls];
        }
        frag_out[9216 + e3] = f2h_bits(acc);
    } else if (e < 11392) {
        const int e2 = e - 11264;           // 0..127
        // row0[k] = R[0,k]; row0[64+k] = L[0,k] - R[0,k]
        row0[e2] = (e2 < 64) ? smg[4096 + e2]
                             : (smg[e2 - 64] - smg[4096 + (e2 - 64)]);
    }
}

// One depth step for both chains (verified R11 body, factored for unrolling).
__device__ __forceinline__ void fractal_step(const f16x8 (&bfr)[4][4],
                                             const f16x8& lfA0, const f16x8& lfA1,
                                             const f16x8& lfB0, const f16x8& lfB1,
                                             i32x4& puA0, i32x4& puA1,
                                             i32x4& puB0, i32x4& puB1) {
    const f16x8 pfA0 = __builtin_bit_cast(f16x8, puA0);
    const f16x8 pfA1 = __builtin_bit_cast(f16x8, puA1);
    const f16x8 pfB0 = __builtin_bit_cast(f16x8, puB0);
    const f16x8 pfB1 = __builtin_bit_cast(f16x8, puB1);
    const f16x8 aA0 = pfA0 * lfA0;   // v_pk_mul_f16
    const f16x8 aA1 = pfA1 * lfA1;
    const f16x8 aB0 = pfB0 * lfB0;
    const f16x8 aB1 = pfB1 * lfB1;
    int PA[4], QA[4], PB[4], QB[4];
#pragma unroll
    for (int t = 0; t < 4; ++t) {
        f32x4 CA = {0.f, 0.f, 0.f, 0.f};
        f32x4 CB = {0.f, 0.f, 0.f, 0.f};
        CA = __builtin_amdgcn_mfma_f32_16x16x32_f16(bfr[t][0], pfA0, CA, 0, 0, 0);
        CB = __builtin_amdgcn_mfma_f32_16x16x32_f16(bfr[t][0], pfB0, CB, 0, 0, 0);
        CA = __builtin_amdgcn_mfma_f32_16x16x32_f16(bfr[t][1], pfA1, CA, 0, 0, 0);
        CB = __builtin_amdgcn_mfma_f32_16x16x32_f16(bfr[t][1], pfB1, CB, 0, 0, 0);
        CA = __builtin_amdgcn_mfma_f32_16x16x32_f16(bfr[t][2], aA0, CA, 0, 0, 0);
        CB = __builtin_amdgcn_mfma_f32_16x16x32_f16(bfr[t][2], aB0, CB, 0, 0, 0);
        CA = __builtin_amdgcn_mfma_f32_16x16x32_f16(bfr[t][3], aA1, CA, 0, 0, 0);
        CB = __builtin_amdgcn_mfma_f32_16x16x32_f16(bfr[t][3], aB1, CB, 0, 0, 0);
        PA[t] = __builtin_bit_cast(int, __builtin_amdgcn_cvt_pkrtz(CA[0], CA[1]));
        QA[t] = __builtin_bit_cast(int, __builtin_amdgcn_cvt_pkrtz(CA[2], CA[3]));
        PB[t] = __builtin_bit_cast(int, __builtin_amdgcn_cvt_pkrtz(CB[0], CB[1]));
        QB[t] = __builtin_bit_cast(int, __builtin_amdgcn_cvt_pkrtz(CB[2], CB[3]));
    }
    // tau labeling: pure register renaming into next state
    puA0.x = PA[0]; puA0.y = QA[0]; puA0.z = PA[1]; puA0.w = QA[1];
    puA1.x = PA[2]; puA1.y = QA[2]; puA1.z = PA[3]; puA1.w = QA[3];
    puB0.x = PB[0]; puB0.y = QB[0]; puB0.z = PB[1]; puB0.w = QB[1];
    puB1.x = PB[2]; puB1.y = QB[2]; puB1.z = PB[3]; puB1.w = QB[3];
}

// ---------------------------------------------------------------------------
// Main: R11 structure, MINUS step 1 (direct init: p1 = R[0,:] + left0*(L-R)[0,:]
// computed in VALU from row0[] — p0 is one-hot so step 1 is not a matmul) and
// MINUS the separate final step + projection (fused: out = p9@(R@Csm) +
// (p9*left)@((L-R)@Csm), 4 MFMAs/chain instead of 16+2). 324 -> 264 MFMA/wave.
// ---------------------------------------------------------------------------
__global__ __launch_bounds__(256, 2)
void fractal_main(const float* __restrict__ x_pos, const float* __restrict__ y_pos,
                  const int* __restrict__ mdp,
                  const unsigned short* __restrict__ frags,
                  const float* __restrict__ tbl,
                  const float* __restrict__ row0,
                  const float* __restrict__ csmg,
                  float* __restrict__ out) {
    const int tid = threadIdx.x;
    const int w = tid >> 6;
    const int l = tid & 63;
    const int q = l >> 4;
    const int m = l & 15;
    const int rowbase = (blockIdx.x * 4 + w) * 32;   // 32 points per wave

    const int md = mdp[0];
    if (md == 0) {
        // p = e0 -> out = Csm[0,:] for every point (then normalize).
        const f32x4 cv = *(const f32x4*)(csmg + 4 * q);
        float s = cv[0] + cv[1] + cv[2] + cv[3];
        s += __shfl_xor(s, 16, 64);
        s += __shfl_xor(s, 32, 64);
        const float inv = 1.0f / fmaxf(s, 1e-10f);
        f32x4 res;
#pragma unroll
        for (int r = 0; r < 4; ++r) res[r] = cv[r] * inv;
        *(f32x4*)(out + (rowbase + m) * 16 + 4 * q) = res;
        *(f32x4*)(out + (rowbase + 16 + m) * 16 + 4 * q) = res;
        return;
    }

    // Resident fragments: [R; L-R] (64 VGPRs), shared by both chains
    const f16x8* __restrict__ fgp = (const f16x8*)frags;
    f16x8 bfr[4][4];
#pragma unroll
    for (int t = 0; t < 4; ++t)
#pragma unroll
        for (int c = 0; c < 4; ++c) bfr[t][c] = fgp[(t * 4 + c) * 64 + l];

    // Vectorized tbl loads
    f32x4 tE0[2], tE1[2], tD0[2], tD1[2];
    tE0[0] = *(const f32x4*)(tbl + 8 * q);       tE0[1] = *(const f32x4*)(tbl + 8 * q + 4);
    tE1[0] = *(const f32x4*)(tbl + 32 + 8 * q);  tE1[1] = *(const f32x4*)(tbl + 32 + 8 * q + 4);
    tD0[0] = *(const f32x4*)(tbl + 64 + 8 * q);  tD0[1] = *(const f32x4*)(tbl + 64 + 8 * q + 4);
    tD1[0] = *(const f32x4*)(tbl + 96 + 8 * q);  tD1[1] = *(const f32x4*)(tbl + 96 + 8 * q + 4);

    const float xA = x_pos[rowbase + m],      yA = y_pos[rowbase + m];
    const float xB = x_pos[rowbase + 16 + m], yB = y_pos[rowbase + 16 + m];
    const float exA = __expf(xA), eyA = __expf(yA);
    const float exB = __expf(xB), eyB = __expf(yB);

    f16x8 lfA0, lfA1, lfB0, lfB1;
#pragma unroll
    for (int j = 0; j < 8; ++j) {
        const float E0 = tE0[j >> 2][j & 3];
        const float E1 = tE1[j >> 2][j & 3];
        const float d0 = tD0[j >> 2][j & 3];
        const float d1 = tD1[j >> 2][j & 3];
        {
            const float h0 = __builtin_amdgcn_rcpf(__builtin_fmaf(exA, E0, 1.0f));
            const float v0 = __builtin_amdgcn_rcpf(__builtin_fmaf(eyA, E0, 1.0f));
            const float h1 = __builtin_amdgcn_rcpf(__builtin_fmaf(exA, E1, 1.0f));
            const float v1 = __builtin_amdgcn_rcpf(__builtin_fmaf(eyA, E1, 1.0f));
            lfA0[j] = (_Float16)(h0 + d0 * (v0 - h0));
            lfA1[j] = (_Float16)(h1 + d1 * (v1 - h1));
        }
        {
            const float h0 = __builtin_amdgcn_rcpf(__builtin_fmaf(exB, E0, 1.0f));
            const float v0 = __builtin_amdgcn_rcpf(__builtin_fmaf(eyB, E0, 1.0f));
            const float h1 = __builtin_amdgcn_rcpf(__builtin_fmaf(exB, E1, 1.0f));
            const float v1 = __builtin_amdgcn_rcpf(__builtin_fmaf(eyB, E1, 1.0f));
            lfB0[j] = (_Float16)(h0 + d0 * (v0 - h0));
            lfB1[j] = (_Float16)(h1 + d1 * (v1 - h1));
        }
    }

    i32x4 puA0, puA1, puB0, puB1;
    if (md >= 2) {
        // Direct step-1 init: p1[k] = R[0,k] + left[b,0]*(L-R)[0,k]
        const float E00 = tbl[0];    // exp(-sp[0])
        const float dir0 = tbl[64];  // sigmoid(sdl[0])
        float lA, lB;
        {
            const float h = __builtin_amdgcn_rcpf(__builtin_fmaf(exA, E00, 1.0f));
            const float v = __builtin_amdgcn_rcpf(__builtin_fmaf(eyA, E00, 1.0f));
            lA = h + dir0 * (v - h);
        }
        {
            const float h = __builtin_amdgcn_rcpf(__builtin_fmaf(exB, E00, 1.0f));
            const float v = __builtin_amdgcn_rcpf(__builtin_fmaf(eyB, E00, 1.0f));
            lB = h + dir0 * (v - h);
        }
        f32x4 rRa[2], rRb[2], rDa[2], rDb[2];
        rRa[0] = *(const f32x4*)(row0 + 8 * q);       rRa[1] = *(const f32x4*)(row0 + 8 * q + 4);
        rRb[0] = *(const f32x4*)(row0 + 32 + 8 * q);  rRb[1] = *(const f32x4*)(row0 + 32 + 8 * q + 4);
        rDa[0] = *(const f32x4*)(row0 + 64 + 8 * q);  rDa[1] = *(const f32x4*)(row0 + 64 + 8 * q + 4);
        rDb[0] = *(const f32x4*)(row0 + 96 + 8 * q);  rDb[1] = *(const f32x4*)(row0 + 96 + 8 * q + 4);
        f16x8 pA0, pA1, pB0, pB1;
#pragma unroll
        for (int j = 0; j < 8; ++j) {
            const float R0 = rRa[j >> 2][j & 3], R1 = rRb[j >> 2][j & 3];
            const float D0 = rDa[j >> 2][j & 3], D1 = rDb[j >> 2][j & 3];
            pA0[j] = (_Float16)__builtin_fmaf(lA, D0, R0);
            pA1[j] = (_Float16)__builtin_fmaf(lA, D1, R1);
            pB0[j] = (_Float16)__builtin_fmaf(lB, D0, R0);
            pB1[j] = (_Float16)__builtin_fmaf(lB, D1, R1);
        }
        puA0 = __builtin_bit_cast(i32x4, pA0);
        puA1 = __builtin_bit_cast(i32x4, pA1);
        puB0 = __builtin_bit_cast(i32x4, pB0);
        puB1 = __builtin_bit_cast(i32x4, pB1);

        if (md == 10) {
#pragma unroll
            for (int d = 0; d < 8; ++d)
                fractal_step(bfr, lfA0, lfA1, lfB0, lfB1, puA0, puA1, puB0, puB1);
        } else {
            for (int d = 0; d < md - 2; ++d)
                fractal_step(bfr, lfA0, lfA1, lfB0, lfB1, puA0, puA1, puB0, puB1);
        }
    } else {  // md == 1: p = e0, fused final does step 1 + projection
        puA0 = (i32x4){0, 0, 0, 0}; puA1 = (i32x4){0, 0, 0, 0};
        puB0 = (i32x4){0, 0, 0, 0}; puB1 = (i32x4){0, 0, 0, 0};
        if (q == 0) { puA0.x = 0x3C00; puB0.x = 0x3C00; }   // f16(1.0)
    }

    // Fused final step + class projection: out^T = [RC; LmRC]^T applied to
    // [p; p*left]. Load fused frags only now (not loop-live).
    f16x8 bfin[4];
#pragma unroll
    for (int f = 0; f < 4; ++f) bfin[f] = fgp[1152 + f * 64 + l];

    {
        const f16x8 pf0 = __builtin_bit_cast(f16x8, puA0);
        const f16x8 pf1 = __builtin_bit_cast(f16x8, puA1);
        const f16x8 a0 = pf0 * lfA0;
        const f16x8 a1 = pf1 * lfA1;
        f32x4 o = {0.f, 0.f, 0.f, 0.f};
        o = __builtin_amdgcn_mfma_f32_16x16x32_f16(bfin[0], pf0, o, 0, 0, 0);
        o = __builtin_amdgcn_mfma_f32_16x16x32_f16(bfin[1], pf1, o, 0, 0, 0);
        o = __builtin_amdgcn_mfma_f32_16x16x32_f16(bfin[2], a0, o, 0, 0, 0);
        o = __builtin_amdgcn_mfma_f32_16x16x32_f16(bfin[3], a1, o, 0, 0, 0);
        float s = o[0] + o[1] + o[2] + o[3];
        s += __shfl_xor(s, 16, 64);
        s += __shfl_xor(s, 32, 64);
        const float inv = 1.0f / fmaxf(s, 1e-10f);
        f32x4 res;
#pragma unroll
        for (int r = 0; r < 4; ++r) res[r] = o[r] * inv;
        *(f32x4*)(out + (rowbase + m) * 16 + 4 * q) = res;
    }
    {
        const f16x8 pf0 = __builtin_bit_cast(f16x8, puB0);
        const f16x8 pf1 = __builtin_bit_cast(f16x8, puB1);
        const f16x8 a0 = pf0 * lfB0;
        const f16x8 a1 = pf1 * lfB1;
        f32x4 o = {0.f, 0.f, 0.f, 0.f};
        o = __builtin_amdgcn_mfma_f32_16x16x32_f16(bfin[0], pf0, o, 0, 0, 0);
        o = __builtin_amdgcn_mfma_f32_16x16x32_f16(bfin[1], pf1, o, 0, 0, 0);
        o = __builtin_amdgcn_mfma_f32_16x16x32_f16(bfin[2], a0, o, 0, 0, 0);
        o = __builtin_amdgcn_mfma_f32_16x16x32_f16(bfin[3], a1, o, 0, 0, 0);
        float s = o[0] + o[1] + o[2] + o[3];
        s += __shfl_xor(s, 16, 64);
        s += __shfl_xor(s, 32, 64);
        const float inv = 1.0f / fmaxf(s, 1e-10f);
        f32x4 res;
#pragma unroll
        for (int r = 0; r < 4; ++r) res[r] = o[r] * inv;
        *(f32x4*)(out + (rowbase + 16 + m) * 16 + 4 * q) = res;
    }
}

extern "C" void kernel_launch(void* const* d_in, const int* in_sizes, int n_in,
                              void* d_out, int out_size, void* d_ws, size_t ws_size,
                              hipStream_t stream) {
    const float* x_pos = (const float*)d_in[0];
    const float* y_pos = (const float*)d_in[1];
    const float* sp    = (const float*)d_in[2];
    const float* sdl   = (const float*)d_in[3];
    const float* cls   = (const float*)d_in[4];
    const float* csl   = (const float*)d_in[5];
    const int*   mdp   = (const int*)d_in[6];

    // d_ws layout:
    //  [0,      22528) frags: 16 main + 2 csm + 4 fused = 11264 halves
    //  [22528,  23040) tbl   (128 f32)
    //  [23040,  23552) row0  (128 f32)
    //  [23552,  56320) smg   (128x64 f32)
    //  [56320,  60416) csmg  (64x16 f32)
    unsigned short* frags = (unsigned short*)d_ws;
    float* tbl  = (float*)((char*)d_ws + 22528);
    float* row0 = (float*)((char*)d_ws + 23040);
    float* smg  = (float*)((char*)d_ws + 23552);
    float* csmg = (float*)((char*)d_ws + 56320);

    fractal_setup_a<<<33, 256, 0, stream>>>(csl, cls, sp, sdl, smg, csmg, tbl);
    fractal_setup_b<<<45, 256, 0, stream>>>(smg, csmg, frags, row0);

    const int B = in_sizes[0];  // 1048576 points; 128 points per block
    fractal_main<<<B / 128, 256, 0, stream>>>(x_pos, y_pos, mdp, frags, tbl, row0,
                                              csmg, (float*)d_out);
}